// Round 5
// baseline (885.777 us; speedup 1.0000x reference)
//
#include <hip/hip_runtime.h>
#include <math.h>

#define BB 16
#define SS 64
#define NN 128
#define FF 16
#define HH 64
#define EE 1024
#define ET 1152   // EE + NN self-loops
#define LLAYERS 2
#define XPAD 65   // 65 % 32 == 1 -> bank = (row+lane)%32, conflict-free everywhere

typedef float v2f __attribute__((ext_vector_type(2)));

__device__ __forceinline__ float readlane_f(float v, int k) {
  return __int_as_float(__builtin_amdgcn_readlane(__float_as_int(v), k));
}
__device__ __forceinline__ float sigmoidf_(float x) { return 1.f / (1.f + expf(-x)); }

// 64-lane sum via DPP (VALU pipe only); result valid in lane 63.
__device__ __forceinline__ float wave_sum64(float x) {
  x += __int_as_float(__builtin_amdgcn_update_dpp(0, __float_as_int(x), 0x111, 0xf, 0xf, true));
  x += __int_as_float(__builtin_amdgcn_update_dpp(0, __float_as_int(x), 0x112, 0xf, 0xf, true));
  x += __int_as_float(__builtin_amdgcn_update_dpp(0, __float_as_int(x), 0x114, 0xf, 0xf, true));
  x += __int_as_float(__builtin_amdgcn_update_dpp(0, __float_as_int(x), 0x118, 0xf, 0xf, true));
  x += __int_as_float(__builtin_amdgcn_update_dpp(0, __float_as_int(x), 0x142, 0xa, 0xf, true)); // bcast15 -> rows 1,3
  x += __int_as_float(__builtin_amdgcn_update_dpp(0, __float_as_int(x), 0x143, 0xc, 0xf, true)); // bcast31 -> rows 2,3
  return x;
}

// ---------------- CSR setup (graph identical for every (b,s)) ----------------
__global__ void setup_csr_kernel(const int* __restrict__ ei,
                                 int* __restrict__ off,
                                 int* __restrict__ csrc) {
  __shared__ int deg[NN], cur[NN], offs[NN + 1];
  int tid = threadIdx.x;
  if (tid < NN) deg[tid] = 0;
  __syncthreads();
  for (int e = tid; e < ET; e += 256) {
    int tg = (e < EE) ? ei[EE + e] : (e - EE);
    atomicAdd(&deg[tg], 1);
  }
  __syncthreads();
  if (tid == 0) {
    int s = 0;
    for (int i = 0; i < NN; ++i) { offs[i] = s; s += deg[i]; }
    offs[NN] = s;
  }
  __syncthreads();
  if (tid < NN) cur[tid] = offs[tid];
  if (tid <= NN) off[tid] = offs[tid];
  __syncthreads();
  for (int e = tid; e < ET; e += 256) {
    int sv, tg;
    if (e < EE) { sv = ei[e]; tg = ei[EE + e]; }
    else        { sv = e - EE; tg = e - EE; }
    int pos = atomicAdd(&cur[tg], 1);
    csrc[pos] = sv;
  }
}

// ---------------- input projection: h = x @ W^T + b --------------------------
__global__ __launch_bounds__(256) void input_proj_kernel(
    const float* __restrict__ x, const float* __restrict__ W,
    const float* __restrict__ bvec, float* __restrict__ h) {
  int lane = threadIdx.x & 63;
  int wid = threadIdx.x >> 6;
  v2f w2[FF / 2];
#pragma unroll
  for (int i = 0; i < FF / 2; ++i) w2[i] = ((const v2f*)(W + lane * FF))[i];
  float bias = bvec[lane];
  int row0 = (blockIdx.x * 4 + wid) * 32;
#pragma unroll 2
  for (int r = 0; r < 32; ++r) {
    const v2f* xr = (const v2f*)(x + (size_t)(row0 + r) * FF);  // wave-uniform
    v2f a0 = {bias, 0.f}, a1 = {0.f, 0.f};
#pragma unroll
    for (int f = 0; f < FF / 2; f += 2) { a0 += xr[f] * w2[f]; a1 += xr[f + 1] * w2[f + 1]; }
    h[(size_t)(row0 + r) * HH + lane] = (a0.x + a1.x) + (a0.y + a1.y);
  }
}

// ---------------- fused GAT layer -------------------------------------------
// Phase 0: xl/xr GEMM. Waves 0,1 -> xl rows 0-63/64-127; waves 2,3 -> xr.
//   Per-lane W row in v2f regs (pk_fma); h rows wave-uniform (s_load path).
//   LDS stride 65: bank=(row+lane)%32 -> conflict-free stores AND gathers.
// Phase 1: wave-per-node over its CSR edge segment. Per edge: one conflict-free
//   ds_read_b32 of xl[src], leaky, att-dot via DPP reduce (VALU, no DS),
//   exp (no max-subtraction: ratio identical, logits bounded), fused
//   accumulate p*xl. No atomics, no second pass, no score matrix.
__global__ __launch_bounds__(256, 2) void gat_fused2_kernel(
    const float* __restrict__ hin, float* __restrict__ hout,
    const int* __restrict__ csr_off, const int* __restrict__ csr_src,
    const float* __restrict__ Wl, const float* __restrict__ bl,
    const float* __restrict__ Wr, const float* __restrict__ br,
    const float* __restrict__ att, const float* __restrict__ bo) {
  __shared__ float xsh[2][NN * XPAD];   // [0]=xl, [1]=xr, 66.6 KB
  int tid = threadIdx.x, lane = tid & 63, wid = tid >> 6;
  int base = blockIdx.x * (NN * HH);
  int half = wid >> 1;                  // 0 -> xl, 1 -> xr
  const float* W  = half ? Wr : Wl;
  const float* bv = half ? br : bl;
  v2f w2[HH / 2];
#pragma unroll
  for (int i = 0; i < HH / 2; ++i) w2[i] = ((const v2f*)(W + lane * HH))[i];
  float bias = bv[lane];
  float* dst = xsh[half];
  int r0 = (wid & 1) * 64;
#pragma unroll 2
  for (int r = r0; r < r0 + 64; ++r) {
    const v2f* hr = (const v2f*)(hin + base + r * HH);   // wave-uniform row
    v2f a0 = {bias, 0.f}, a1 = {0.f, 0.f};
#pragma unroll
    for (int k = 0; k < HH / 2; k += 2) { a0 += hr[k] * w2[k]; a1 += hr[k + 1] * w2[k + 1]; }
    dst[r * XPAD + lane] = (a0.x + a1.x) + (a0.y + a1.y);
  }
  float att_l = att[lane], bo_l = bo[lane];
  __syncthreads();

#pragma unroll 1
  for (int n = wid; n < NN; n += 4) {
    int o0 = csr_off[n], o1 = csr_off[n + 1];            // uniform -> s_load
    float xrv = xsh[1][n * XPAD + lane];
    float z = 0.f, acc = 0.f;
    int s0 = csr_src[o0];
    float xln = xsh[0][s0 * XPAD + lane];
#pragma unroll 1
    for (int i = o0; i < o1; ++i) {
      float xlv = xln;
      if (i + 1 < o1) {                                  // pipeline next edge
        int s2 = csr_src[i + 1];
        xln = xsh[0][s2 * XPAD + lane];
      }
      float v = xlv + xrv;
      v = fmaxf(v, 0.2f * v);                            // leaky_relu(0.2)
      float a = readlane_f(wave_sum64(v * att_l), 63);
      float p = expf(a);                                 // stable: |a| small
      z += p;
      acc = fmaf(p, xlv, acc);
    }
    hout[base + n * HH + lane] = fmaxf(acc / z + bo_l, 0.f);
  }
}

// ---------------- GRU: producer-consumer, packed math ------------------------
// Wave 0 (producer): 3 Wih rows/lane in v2f regs; x_t via wave-uniform loads
//   (s_load path); gi(t+1) one step ahead into 2-slot LDS ring.
// Wave 1 (consumer): 3 Whh rows/lane in v2f regs; h broadcast via wave-uniform
//   v2f LDS reads feeding v_pk_fma. One barrier/step.
// __launch_bounds__(128,1): 512-VGPR cap so the 192-float weight arrays stay
//   register-resident (R4's (128,2) made the allocator rematerialize from L1:
//   VGPR_Count was 112 < 192); ~230 VGPRs still gives 2 waves/SIMD.
__global__ __launch_bounds__(128, 1) void gru_pc2_kernel(
    const float* __restrict__ hbuf,
    const float* __restrict__ Wih, const float* __restrict__ Whh,
    const float* __restrict__ bih, const float* __restrict__ bhh,
    const float* __restrict__ oW1, const float* __restrict__ ob1,
    const float* __restrict__ oW2, const float* __restrict__ ob2,
    const float* __restrict__ dW1, const float* __restrict__ db1,
    const float* __restrict__ dW2, const float* __restrict__ db2,
    float* __restrict__ out) {
  int lane = threadIdx.x & 63;
  int w = (int)threadIdx.x >> 6;       // 0 = producer, 1 = consumer
  int seq = blockIdx.x;                // b*N + n
  int b = seq >> 7, n = seq & (NN - 1);

  __shared__ float ring[2][3][HH];     // gi double-buffer
  __shared__ float hbr[2][HH];         // h broadcast double-buffer

  const float* Ws = w ? Whh : Wih;
  const float* Bs = w ? bhh : bih;
  v2f wt[3][HH / 2];                   // 192 floats, register-resident
#pragma unroll
  for (int g = 0; g < 3; ++g) {
    const v2f* src = (const v2f*)(Ws + (size_t)(g * 64 + lane) * HH);
#pragma unroll
    for (int i = 0; i < HH / 2; ++i) wt[g][i] = src[i];
  }
  float b_r = Bs[lane], b_z = Bs[64 + lane], b_n = Bs[128 + lane];
  const float* xbase = hbuf + ((size_t)(b * SS) * NN + n) * HH;
  float hj = 0.f;

  if (w == 0) {                        // prologue: gi(0) -> ring[0]
    const v2f* xr = (const v2f*)xbase; // wave-uniform
    v2f ar = {b_r, 0.f}, az = {b_z, 0.f}, an = {b_n, 0.f};
#pragma unroll
    for (int k = 0; k < HH / 2; ++k) {
      v2f xv = xr[k];
      ar += xv * wt[0][k]; az += xv * wt[1][k]; an += xv * wt[2][k];
    }
    ring[0][0][lane] = ar.x + ar.y;
    ring[0][1][lane] = az.x + az.y;
    ring[0][2][lane] = an.x + an.y;
  } else {
    hbr[0][lane] = 0.f;
  }
  __syncthreads();

#pragma unroll 1
  for (int t = 0; t < SS; ++t) {
    if (w == 0) {
      if (t + 1 < SS) {
        const v2f* xr = (const v2f*)(xbase + (size_t)(t + 1) * NN * HH);
        v2f ar = {b_r, 0.f}, az = {b_z, 0.f}, an = {b_n, 0.f};
#pragma unroll
        for (int k = 0; k < HH / 2; ++k) {
          v2f xv = xr[k];
          ar += xv * wt[0][k]; az += xv * wt[1][k]; an += xv * wt[2][k];
        }
        int sl = (t + 1) & 1;
        ring[sl][0][lane] = ar.x + ar.y;
        ring[sl][1][lane] = az.x + az.y;
        ring[sl][2][lane] = an.x + an.y;
      }
    } else {
      int sl = t & 1;
      float gir = ring[sl][0][lane];
      float giz = ring[sl][1][lane];
      float gin = ring[sl][2][lane];
      const v2f* hb2 = (const v2f*)hbr[sl];              // wave-uniform bcast
      v2f ar = {b_r, 0.f}, az = {b_z, 0.f}, an = {b_n, 0.f};
#pragma unroll
      for (int k = 0; k < HH / 2; ++k) {
        v2f hv = hb2[k];
        ar += hv * wt[0][k]; az += hv * wt[1][k]; an += hv * wt[2][k];
      }
      float ghr = ar.x + ar.y, ghz = az.x + az.y, ghn = an.x + an.y;
      float rg = sigmoidf_(gir + ghr);
      float zg = sigmoidf_(giz + ghz);
      float ng = tanhf(gin + rg * ghn);
      hj = (1.f - zg) * ng + zg * hj;
      hbr[(t + 1) & 1][lane] = hj;                       // same-wave: no barrier
    }
    __syncthreads();
  }

  // fused heads on consumer wave: lanes 0-31 order head, 32-63 demand head
  if (w == 1) {
    const float* hs = hbr[SS & 1];                       // h_63 lives in slot 0
    int hf = lane >> 5, jp = lane & 31;
    const float* W1 = hf ? dW1 : oW1;
    const float* b1 = hf ? db1 : ob1;
    const float* W2 = hf ? dW2 : oW2;
    const float* b2 = hf ? db2 : ob2;
    v2f wv[HH / 2];
#pragma unroll
    for (int i = 0; i < HH / 2; ++i) wv[i] = ((const v2f*)(W1 + jp * HH))[i];
    v2f a2 = {b1[jp], 0.f};
#pragma unroll
    for (int k = 0; k < HH / 2; ++k) a2 += ((const v2f*)hs)[k] * wv[k];
    float val = fmaxf(a2.x + a2.y, 0.f) * W2[jp];
    val += __shfl_down(val, 16, 32);
    val += __shfl_down(val, 8, 32);
    val += __shfl_down(val, 4, 32);
    val += __shfl_down(val, 2, 32);
    val += __shfl_down(val, 1, 32);
    if (jp == 0) out[hf * (BB * NN) + seq] = val + b2[0];
  }
}

// ---------------- launch -----------------------------------------------------
extern "C" void kernel_launch(void* const* d_in, const int* in_sizes, int n_in,
                              void* d_out, int out_size, void* d_ws, size_t ws_size,
                              hipStream_t stream) {
  const float* x       = (const float*)d_in[0];
  const int*   ei      = (const int*)d_in[1];
  const float* in_W    = (const float*)d_in[2];
  const float* in_b    = (const float*)d_in[3];
  const float* gat_Wl  = (const float*)d_in[4];
  const float* gat_bl  = (const float*)d_in[5];
  const float* gat_Wr  = (const float*)d_in[6];
  const float* gat_br  = (const float*)d_in[7];
  const float* gat_att = (const float*)d_in[8];
  const float* gat_bias= (const float*)d_in[9];
  const float* gru_Wih = (const float*)d_in[10];
  const float* gru_Whh = (const float*)d_in[11];
  const float* gru_bih = (const float*)d_in[12];
  const float* gru_bhh = (const float*)d_in[13];
  const float* oh_W1   = (const float*)d_in[14];
  const float* oh_b1   = (const float*)d_in[15];
  const float* oh_W2   = (const float*)d_in[16];
  const float* oh_b2   = (const float*)d_in[17];
  const float* dh_W1   = (const float*)d_in[18];
  const float* dh_b1   = (const float*)d_in[19];
  const float* dh_W2   = (const float*)d_in[20];
  const float* dh_b2   = (const float*)d_in[21];
  float* out = (float*)d_out;

  char* ws = (char*)d_ws;
  size_t hbytes = (size_t)BB * SS * NN * HH * sizeof(float);   // 33.5 MB
  float* hA = (float*)ws;
  int* csr_off = (int*)(ws + hbytes);
  int* csr_src = csr_off + 160;
  size_t off_hB = hbytes + (160 + ET) * sizeof(int);
  off_hB = (off_hB + 255) & ~(size_t)255;
  // ping-pong buffer (ws is known >= 134 MB from earlier rounds; fall back
  // to in-place if tight — per-block read/write separation + __syncthreads
  // makes in-place safe too)
  float* hB = (ws_size >= off_hB + hbytes) ? (float*)(ws + off_hB) : hA;

  setup_csr_kernel<<<1, 256, 0, stream>>>(ei, csr_off, csr_src);
  input_proj_kernel<<<(BB * SS * NN) / (4 * 32), 256, 0, stream>>>(x, in_W, in_b, hA);
  // layer 0: A -> B ; layer 1: B -> A
  gat_fused2_kernel<<<BB * SS, 256, 0, stream>>>(
      hA, hB, csr_off, csr_src,
      gat_Wl, gat_bl, gat_Wr, gat_br, gat_att, gat_bias);
  gat_fused2_kernel<<<BB * SS, 256, 0, stream>>>(
      hB, hA, csr_off, csr_src,
      gat_Wl + HH * HH, gat_bl + HH, gat_Wr + HH * HH, gat_br + HH,
      gat_att + HH, gat_bias + HH);
  gru_pc2_kernel<<<BB * NN, 128, 0, stream>>>(
      hA, gru_Wih, gru_Whh, gru_bih, gru_bhh,
      oh_W1, oh_b1, oh_W2, oh_b2, dh_W1, dh_b1, dh_W2, dh_b2, out);
}

// Round 6
// 844.668 us; speedup vs baseline: 1.0487x; 1.0487x over previous
//
#include <hip/hip_runtime.h>
#include <math.h>

#define BB 16
#define SS 64
#define NN 128
#define FF 16
#define HH 64
#define EE 1024
#define ET 1152   // EE + NN self-loops
#define XPAD 65   // 65 % 32 == 1: bank = (row+lane)%32 -> conflict-free gather,
                  // ~2-way random for per-edge reads (measured 0 conflicts in R2/R5)

typedef float v2f __attribute__((ext_vector_type(2)));

__device__ __forceinline__ float sigmoidf_(float x) { return 1.f / (1.f + expf(-x)); }

// ---------------- CSR setup (graph identical for every (b,s)) ----------------
__global__ void setup_csr_kernel(const int* __restrict__ ei,
                                 int* __restrict__ off,
                                 int* __restrict__ csrc,
                                 int* __restrict__ ctgt) {
  __shared__ int deg[NN], cur[NN], offs[NN + 1];
  int tid = threadIdx.x;
  if (tid < NN) deg[tid] = 0;
  __syncthreads();
  for (int e = tid; e < ET; e += 256) {
    int tg = (e < EE) ? ei[EE + e] : (e - EE);
    atomicAdd(&deg[tg], 1);
  }
  __syncthreads();
  if (tid == 0) {
    int s = 0;
    for (int i = 0; i < NN; ++i) { offs[i] = s; s += deg[i]; }
    offs[NN] = s;
  }
  __syncthreads();
  if (tid < NN) cur[tid] = offs[tid];
  if (tid <= NN) off[tid] = offs[tid];
  __syncthreads();
  for (int e = tid; e < ET; e += 256) {
    int sv, tg;
    if (e < EE) { sv = ei[e]; tg = ei[EE + e]; }
    else        { sv = e - EE; tg = e - EE; }
    int pos = atomicAdd(&cur[tg], 1);
    csrc[pos] = sv;
    ctgt[pos] = tg;
  }
}

// ---------------- input projection: h = x @ W^T + b --------------------------
__global__ __launch_bounds__(256) void input_proj_kernel(
    const float* __restrict__ x, const float* __restrict__ W,
    const float* __restrict__ bvec, float* __restrict__ h) {
  int lane = threadIdx.x & 63;
  int wid = threadIdx.x >> 6;
  v2f w2[FF / 2];
#pragma unroll
  for (int i = 0; i < FF / 2; ++i) w2[i] = ((const v2f*)(W + lane * FF))[i];
  float bias = bvec[lane];
  int row0 = (blockIdx.x * 4 + wid) * 32;
#pragma unroll 2
  for (int r = 0; r < 32; ++r) {
    const v2f* xr = (const v2f*)(x + (size_t)(row0 + r) * FF);  // wave-uniform
    v2f a0 = {bias, 0.f}, a1 = {0.f, 0.f};
#pragma unroll
    for (int f = 0; f < FF / 2; f += 2) { a0 += xr[f] * w2[f]; a1 += xr[f + 1] * w2[f + 1]; }
    h[(size_t)(row0 + r) * HH + lane] = (a0.x + a1.x) + (a0.y + a1.y);
  }
}

// ---------------- fused GAT layer (in-place) ---------------------------------
// Phase 0: xl/xr GEMM (waves 0,1 -> xl; 2,3 -> xr), per-lane W row in regs,
//   h rows wave-uniform. LDS stride 65: conflict-free stores and gathers.
// Phase 1: THREAD-per-edge logits (R2 structure: 64 independent edges in
//   flight per wave, no cross-lane ops, no serial chains). att via uniform
//   scalar loads; softmax without max-subtraction (validated bit-exact R5).
// Phase 2: wave-per-node CSR gather, conflict-free column reads.
__global__ __launch_bounds__(256, 2) void gat_fused3_kernel(
    float* hio,
    const int* __restrict__ csr_off, const int* __restrict__ csr_src,
    const int* __restrict__ csr_tgt,
    const float* __restrict__ Wl, const float* __restrict__ bl,
    const float* __restrict__ Wr, const float* __restrict__ br,
    const float* __restrict__ att, const float* __restrict__ bo) {
  __shared__ float xsh[2][NN * XPAD];   // 66.6 KB: [0]=xl, [1]=xr
  __shared__ float p_sh[ET];            // 4.6 KB
  __shared__ int st_sh[ET];             // 4.6 KB: src | tgt<<16
  int tid = threadIdx.x, lane = tid & 63, wid = tid >> 6;
  int base = blockIdx.x * (NN * HH);

  for (int i = tid; i < ET; i += 256)
    st_sh[i] = csr_src[i] | (csr_tgt[i] << 16);

  // phase 0: GEMM into LDS
  int half = wid >> 1;                  // 0 -> xl, 1 -> xr
  const float* W  = half ? Wr : Wl;
  const float* bv = half ? br : bl;
  v2f w2[HH / 2];
#pragma unroll
  for (int i = 0; i < HH / 2; ++i) w2[i] = ((const v2f*)(W + lane * HH))[i];
  float bias = bv[lane];
  float* dst = xsh[half];
  int r0 = (wid & 1) * 64;
#pragma unroll 2
  for (int r = r0; r < r0 + 64; ++r) {
    const v2f* hr = (const v2f*)(hio + base + r * HH);   // wave-uniform row
    v2f a0 = {bias, 0.f}, a1 = {0.f, 0.f};
#pragma unroll
    for (int k = 0; k < HH / 2; k += 2) { a0 += hr[k] * w2[k]; a1 += hr[k + 1] * w2[k + 1]; }
    dst[r * XPAD + lane] = (a0.x + a1.x) + (a0.y + a1.y);
  }
  float bo_l = bo[lane];
  __syncthreads();

  // phase 1: thread-per-edge logits + exp
#pragma unroll 1
  for (int e = tid; e < ET; e += 256) {
    int st = st_sh[e];
    int s = st & 0xffff, tg = st >> 16;
    const float* xlr = xsh[0] + s * XPAD;
    const float* xrr = xsh[1] + tg * XPAD;
    v2f a0 = {0.f, 0.f}, a1 = {0.f, 0.f};
#pragma unroll
    for (int k = 0; k < HH; k += 4) {
      v2f l0 = *(const v2f*)(xlr + k),     rr0 = *(const v2f*)(xrr + k);
      v2f l1 = *(const v2f*)(xlr + k + 2), rr1 = *(const v2f*)(xrr + k + 2);
      v2f v0 = l0 + rr0, v1 = l1 + rr1;
      v0.x = fmaxf(v0.x, 0.2f * v0.x); v0.y = fmaxf(v0.y, 0.2f * v0.y);
      v1.x = fmaxf(v1.x, 0.2f * v1.x); v1.y = fmaxf(v1.y, 0.2f * v1.y);
      v2f at0 = *(const v2f*)(att + k);      // uniform -> scalar loads
      v2f at1 = *(const v2f*)(att + k + 2);
      a0 += v0 * at0; a1 += v1 * at1;
    }
    p_sh[e] = expf((a0.x + a0.y) + (a1.x + a1.y));   // stable: logits bounded
  }
  __syncthreads();

  // phase 2: wave-per-node gather over CSR segment
#pragma unroll 1
  for (int n = wid; n < NN; n += 4) {
    int o0 = csr_off[n], o1 = csr_off[n + 1];        // uniform
    float acc = 0.f, z = 0.f;
    for (int i = o0; i < o1; ++i) {
      float p = p_sh[i];                              // broadcast
      int s = st_sh[i] & 0xffff;
      acc = fmaf(p, xsh[0][s * XPAD + lane], acc);    // conflict-free column
      z += p;
    }
    hio[base + n * HH + lane] = fmaxf(acc / z + bo_l, 0.f);
  }
}

// ---------------- GRU: 3 waves = gates r/z/n, wave-specialized ---------------
// Wave g holds ONLY gate g's Wih+Whh rows (128 floats/lane) -> register-
// resident without extreme occupancy bounds. gi computed in-loop from
// wave-uniform x loads (SMEM path; its latency overlaps the gh LDS chain).
// h broadcast via same-address LDS reads. 2 barriers/step.
__global__ __launch_bounds__(192, 2) void gru_ws3_kernel(
    const float* __restrict__ hbuf,
    const float* __restrict__ Wih, const float* __restrict__ Whh,
    const float* __restrict__ bih, const float* __restrict__ bhh,
    const float* __restrict__ oW1, const float* __restrict__ ob1,
    const float* __restrict__ oW2, const float* __restrict__ ob2,
    const float* __restrict__ dW1, const float* __restrict__ db1,
    const float* __restrict__ dW2, const float* __restrict__ db2,
    float* __restrict__ out) {
  int lane = threadIdx.x & 63;
  int g = (int)threadIdx.x >> 6;       // 0=r, 1=z, 2=n
  int seq = blockIdx.x;                // b*N + n
  int b = seq >> 7, n = seq & (NN - 1);

  v2f wih[HH / 2], whh[HH / 2];        // 128 floats, register-resident
  {
    const v2f* si = (const v2f*)(Wih + (size_t)(g * 64 + lane) * HH);
    const v2f* sh = (const v2f*)(Whh + (size_t)(g * 64 + lane) * HH);
#pragma unroll
    for (int i = 0; i < HH / 2; ++i) { wih[i] = si[i]; whh[i] = sh[i]; }
  }
  float bi = bih[g * 64 + lane], bh = bhh[g * 64 + lane];

  __shared__ float hbr[2][HH];         // h double-buffer
  __shared__ float r_sh[HH], z_sh[HH];
  const float* xbase = hbuf + ((size_t)(b * SS) * NN + n) * HH;
  float hj = 0.f;                      // live state on wave 2 only
  if (g == 2) hbr[0][lane] = 0.f;
  __syncthreads();

#pragma unroll 1
  for (int t = 0; t < SS; ++t) {
    // gi: issue uniform x loads first (latency overlaps gh chain)
    const v2f* xr = (const v2f*)(xbase + (size_t)t * NN * HH);
    v2f gia = {bi, 0.f}, gib = {0.f, 0.f};
#pragma unroll
    for (int k = 0; k < HH / 2; k += 2) {
      gia += xr[k] * wih[k];
      gib += xr[k + 1] * wih[k + 1];
    }
    // gh: same-address LDS broadcast of h
    const v2f* hb = (const v2f*)hbr[t & 1];
    v2f gha = {bh, 0.f}, ghb = {0.f, 0.f};
#pragma unroll
    for (int k = 0; k < HH / 2; k += 2) {
      gha += hb[k] * whh[k];
      ghb += hb[k + 1] * whh[k + 1];
    }
    float gi = (gia.x + gia.y) + (gib.x + gib.y);
    float gh = (gha.x + gha.y) + (ghb.x + ghb.y);
    if (g == 0)      r_sh[lane] = sigmoidf_(gi + gh);
    else if (g == 1) z_sh[lane] = sigmoidf_(gi + gh);
    __syncthreads();
    if (g == 2) {
      float rg = r_sh[lane], zg = z_sh[lane];
      float ng = tanhf(gi + rg * gh);
      hj = (1.f - zg) * ng + zg * hj;
      hbr[(t + 1) & 1][lane] = hj;
    }
    __syncthreads();
  }

  // fused heads on wave 0: lanes 0-31 order head, 32-63 demand head
  if (g == 0) {
    const float* hs = hbr[SS & 1];     // h_last (SS even -> slot 0)
    int hf = lane >> 5, jp = lane & 31;
    const float* W1 = hf ? dW1 : oW1;
    const float* b1 = hf ? db1 : ob1;
    const float* W2 = hf ? dW2 : oW2;
    const float* b2 = hf ? db2 : ob2;
    v2f wv[HH / 2];
#pragma unroll
    for (int i = 0; i < HH / 2; ++i) wv[i] = ((const v2f*)(W1 + jp * HH))[i];
    v2f a2 = {b1[jp], 0.f};
#pragma unroll
    for (int k = 0; k < HH / 2; ++k) a2 += ((const v2f*)hs)[k] * wv[k];
    float val = fmaxf(a2.x + a2.y, 0.f) * W2[jp];
    val += __shfl_down(val, 16, 32);
    val += __shfl_down(val, 8, 32);
    val += __shfl_down(val, 4, 32);
    val += __shfl_down(val, 2, 32);
    val += __shfl_down(val, 1, 32);
    if (jp == 0) out[hf * (BB * NN) + seq] = val + b2[0];
  }
}

// ---------------- launch -----------------------------------------------------
extern "C" void kernel_launch(void* const* d_in, const int* in_sizes, int n_in,
                              void* d_out, int out_size, void* d_ws, size_t ws_size,
                              hipStream_t stream) {
  const float* x       = (const float*)d_in[0];
  const int*   ei      = (const int*)d_in[1];
  const float* in_W    = (const float*)d_in[2];
  const float* in_b    = (const float*)d_in[3];
  const float* gat_Wl  = (const float*)d_in[4];
  const float* gat_bl  = (const float*)d_in[5];
  const float* gat_Wr  = (const float*)d_in[6];
  const float* gat_br  = (const float*)d_in[7];
  const float* gat_att = (const float*)d_in[8];
  const float* gat_bias= (const float*)d_in[9];
  const float* gru_Wih = (const float*)d_in[10];
  const float* gru_Whh = (const float*)d_in[11];
  const float* gru_bih = (const float*)d_in[12];
  const float* gru_bhh = (const float*)d_in[13];
  const float* oh_W1   = (const float*)d_in[14];
  const float* oh_b1   = (const float*)d_in[15];
  const float* oh_W2   = (const float*)d_in[16];
  const float* oh_b2   = (const float*)d_in[17];
  const float* dh_W1   = (const float*)d_in[18];
  const float* dh_b1   = (const float*)d_in[19];
  const float* dh_W2   = (const float*)d_in[20];
  const float* dh_b2   = (const float*)d_in[21];
  float* out = (float*)d_out;

  char* ws = (char*)d_ws;
  size_t hbytes = (size_t)BB * SS * NN * HH * sizeof(float);   // 33.5 MB
  float* hbuf = (float*)ws;
  int* csr_off = (int*)(ws + hbytes);
  int* csr_src = csr_off + 160;
  int* csr_tgt = csr_src + ET;

  setup_csr_kernel<<<1, 256, 0, stream>>>(ei, csr_off, csr_src, csr_tgt);
  input_proj_kernel<<<(BB * SS * NN) / (4 * 32), 256, 0, stream>>>(x, in_W, in_b, hbuf);
  gat_fused3_kernel<<<BB * SS, 256, 0, stream>>>(
      hbuf, csr_off, csr_src, csr_tgt,
      gat_Wl, gat_bl, gat_Wr, gat_br, gat_att, gat_bias);
  gat_fused3_kernel<<<BB * SS, 256, 0, stream>>>(
      hbuf, csr_off, csr_src, csr_tgt,
      gat_Wl + HH * HH, gat_bl + HH, gat_Wr + HH * HH, gat_br + HH,
      gat_att + HH, gat_bias + HH);
  gru_ws3_kernel<<<BB * NN, 192, 0, stream>>>(
      hbuf, gru_Wih, gru_Whh, gru_bih, gru_bhh,
      oh_W1, oh_b1, oh_W2, oh_b2, dh_W1, dh_b1, dh_W2, dh_b2, out);
}

// Round 7
// 794.660 us; speedup vs baseline: 1.1147x; 1.0629x over previous
//
#include <hip/hip_runtime.h>
#include <math.h>

#define BB 16
#define SS 64
#define NN 128
#define FF 16
#define HH 64
#define EE 1024
#define ET 1152   // EE + NN self-loops
#define XPAD 65   // 65 % 32 == 1: conflict-free column gather (measured 0 conflicts)

typedef float v2f __attribute__((ext_vector_type(2)));

__device__ __forceinline__ float sigmoidf_(float x) { return 1.f / (1.f + expf(-x)); }
__device__ __forceinline__ float sum4(float4 a) { return (a.x + a.y) + (a.z + a.w); }

// ---------------- CSR setup (graph identical for every (b,s)) ----------------
__global__ void setup_csr_kernel(const int* __restrict__ ei,
                                 int* __restrict__ off,
                                 int* __restrict__ csrc,
                                 int* __restrict__ ctgt) {
  __shared__ int deg[NN], cur[NN], offs[NN + 1];
  int tid = threadIdx.x;
  if (tid < NN) deg[tid] = 0;
  __syncthreads();
  for (int e = tid; e < ET; e += 256) {
    int tg = (e < EE) ? ei[EE + e] : (e - EE);
    atomicAdd(&deg[tg], 1);
  }
  __syncthreads();
  if (tid == 0) {
    int s = 0;
    for (int i = 0; i < NN; ++i) { offs[i] = s; s += deg[i]; }
    offs[NN] = s;
  }
  __syncthreads();
  if (tid < NN) cur[tid] = offs[tid];
  if (tid <= NN) off[tid] = offs[tid];
  __syncthreads();
  for (int e = tid; e < ET; e += 256) {
    int sv, tg;
    if (e < EE) { sv = ei[e]; tg = ei[EE + e]; }
    else        { sv = e - EE; tg = e - EE; }
    int pos = atomicAdd(&cur[tg], 1);
    csrc[pos] = sv;
    ctgt[pos] = tg;
  }
}

// ---------------- input projection: h = x @ W^T + b --------------------------
// Coalesced stage of 128 rows (2 KB... 8 KB) into LDS, then b128 broadcasts.
__global__ __launch_bounds__(256) void input_proj2_kernel(
    const float* __restrict__ x, const float* __restrict__ W,
    const float* __restrict__ bvec, float* __restrict__ h) {
  __shared__ __align__(16) float xs[128 * FF];   // 8 KB
  int tid = threadIdx.x, lane = tid & 63, wid = tid >> 6;
  size_t base = (size_t)blockIdx.x * (128 * FF);
  // stage 2048 floats coalesced
  *(float4*)&xs[tid * 4]        = *(const float4*)(x + base + tid * 4);
  *(float4*)&xs[tid * 4 + 1024] = *(const float4*)(x + base + tid * 4 + 1024);
  float4 w4[FF / 4];
#pragma unroll
  for (int i = 0; i < FF / 4; ++i) w4[i] = ((const float4*)(W + lane * FF))[i];
  float bias = bvec[lane];
  __syncthreads();
  int r0 = wid * 32;
#pragma unroll 4
  for (int r = r0; r < r0 + 32; ++r) {
    const float4* xr = (const float4*)&xs[r * FF];   // LDS broadcast
    float4 a = {bias, 0.f, 0.f, 0.f};
#pragma unroll
    for (int f = 0; f < FF / 4; ++f) a += xr[f] * w4[f];
    h[(size_t)blockIdx.x * (128 * HH) + (size_t)r * HH + lane] = sum4(a);
  }
}

// ---------------- fused GAT layer (in-place) ---------------------------------
// Phase 0: h staged in 8-row chunks via coalesced float4 (prefetched one chunk
//   ahead in registers); each wave computes xl AND xr for 2 rows/chunk from
//   b128 LDS broadcasts, both weight sets in VGPRs. No uniform global loads.
// Phase 1: thread-per-edge logits (R6, proven). Phase 2: pipelined CSR gather.
__global__ __launch_bounds__(256, 2) void gat_fused4_kernel(
    float* hio,
    const int* __restrict__ csr_off, const int* __restrict__ csr_src,
    const int* __restrict__ csr_tgt,
    const float* __restrict__ Wl, const float* __restrict__ bl,
    const float* __restrict__ Wr, const float* __restrict__ br,
    const float* __restrict__ att, const float* __restrict__ bo) {
  __shared__ __align__(16) float xsh[2][NN * XPAD];  // 66.6 KB: [0]=xl, [1]=xr
  __shared__ __align__(16) float p_hst[ET];          // phase0: h-chunk; phase1+: p
  __shared__ int st_sh[ET];                          // src | tgt<<16
  int tid = threadIdx.x, lane = tid & 63, wid = tid >> 6;
  size_t base = (size_t)blockIdx.x * (NN * HH);

  for (int i = tid; i < ET; i += 256)
    st_sh[i] = csr_src[i] | (csr_tgt[i] << 16);

  // per-lane weight rows for BOTH projections (128 VGPRs)
  float4 wl4[HH / 4], wr4[HH / 4];
#pragma unroll
  for (int i = 0; i < HH / 4; ++i) {
    wl4[i] = ((const float4*)(Wl + lane * HH))[i];
    wr4[i] = ((const float4*)(Wr + lane * HH))[i];
  }
  float bl_l = bl[lane], br_l = br[lane];

  // phase 0: 16 chunks x 8 rows; register-prefetch next chunk
  float4 f4;
  if (tid < 128) f4 = *(const float4*)(hio + base + tid * 4);
#pragma unroll 1
  for (int c = 0; c < 16; ++c) {
    __syncthreads();                        // prev compute done with p_hst
    if (tid < 128) *(float4*)&p_hst[tid * 4] = f4;
    if (c < 15 && tid < 128)
      f4 = *(const float4*)(hio + base + (c + 1) * 512 + tid * 4);
    __syncthreads();                        // chunk staged
    int rl = wid * 2;                       // 2 rows per wave
#pragma unroll
    for (int rr = 0; rr < 2; ++rr) {
      const float4* hr = (const float4*)&p_hst[(rl + rr) * HH];  // broadcast
      float4 al = {bl_l, 0.f, 0.f, 0.f}, ar = {br_l, 0.f, 0.f, 0.f};
#pragma unroll
      for (int k = 0; k < HH / 4; ++k) {
        float4 hv = hr[k];
        al += hv * wl4[k];
        ar += hv * wr4[k];
      }
      int r = c * 8 + rl + rr;
      xsh[0][r * XPAD + lane] = sum4(al);
      xsh[1][r * XPAD + lane] = sum4(ar);
    }
  }
  float bo_l = bo[lane];
  __syncthreads();

  // phase 1: thread-per-edge logits + exp (no max-subtraction; validated)
#pragma unroll 1
  for (int e = tid; e < ET; e += 256) {
    int st = st_sh[e];
    int s = st & 0xffff, tg = st >> 16;
    const float* xlr = xsh[0] + s * XPAD;
    const float* xrr = xsh[1] + tg * XPAD;
    v2f a0 = {0.f, 0.f}, a1 = {0.f, 0.f};
#pragma unroll
    for (int k = 0; k < HH; k += 4) {
      v2f l0 = *(const v2f*)(xlr + k),     rr0 = *(const v2f*)(xrr + k);
      v2f l1 = *(const v2f*)(xlr + k + 2), rr1 = *(const v2f*)(xrr + k + 2);
      v2f v0 = l0 + rr0, v1 = l1 + rr1;
      v0.x = fmaxf(v0.x, 0.2f * v0.x); v0.y = fmaxf(v0.y, 0.2f * v0.y);
      v1.x = fmaxf(v1.x, 0.2f * v1.x); v1.y = fmaxf(v1.y, 0.2f * v1.y);
      v2f at0 = *(const v2f*)(att + k);       // uniform -> scalar loads
      v2f at1 = *(const v2f*)(att + k + 2);
      a0 += v0 * at0; a1 += v1 * at1;
    }
    p_hst[e] = expf((a0.x + a0.y) + (a1.x + a1.y));
  }
  __syncthreads();

  // phase 2: wave-per-node pipelined gather over CSR segment
#pragma unroll 1
  for (int n = wid; n < NN; n += 4) {
    int o0 = csr_off[n], o1 = csr_off[n + 1];   // uniform
    float acc = 0.f, z = 0.f;
    int st = st_sh[o0];
    float xln = xsh[0][(st & 0xffff) * XPAD + lane];
    float pn = p_hst[o0];
#pragma unroll 1
    for (int i = o0; i < o1; ++i) {
      float xlv = xln, p = pn;
      if (i + 1 < o1) {                         // pipeline next edge
        int st2 = st_sh[i + 1];
        xln = xsh[0][(st2 & 0xffff) * XPAD + lane];
        pn = p_hst[i + 1];
      }
      acc = fmaf(p, xlv, acc);
      z += p;
    }
    hio[base + n * HH + lane] = fmaxf(acc / z + bo_l, 0.f);
  }
}

// ---------------- GRU: 3 gate waves + LDS x-ring -----------------------------
// Wave g holds gate g's Wih+Whh rows (128 floats/lane, register-resident).
// Wave 0 prefetches x_{t+1} with ONE coalesced dword into a 2-slot LDS ring;
// all waves read x and h via b128 LDS broadcasts. No uniform global loads.
__global__ __launch_bounds__(192, 2) void gru_ws4_kernel(
    const float* __restrict__ hbuf,
    const float* __restrict__ Wih, const float* __restrict__ Whh,
    const float* __restrict__ bih, const float* __restrict__ bhh,
    const float* __restrict__ oW1, const float* __restrict__ ob1,
    const float* __restrict__ oW2, const float* __restrict__ ob2,
    const float* __restrict__ dW1, const float* __restrict__ db1,
    const float* __restrict__ dW2, const float* __restrict__ db2,
    float* __restrict__ out) {
  int lane = threadIdx.x & 63;
  int g = (int)threadIdx.x >> 6;       // 0=r, 1=z, 2=n
  int seq = blockIdx.x;                // b*N + n
  int b = seq >> 7, n = seq & (NN - 1);

  float4 wi4[HH / 4], wh4[HH / 4];     // 128 floats, register-resident
  {
    const float4* si = (const float4*)(Wih + (size_t)(g * 64 + lane) * HH);
    const float4* sh = (const float4*)(Whh + (size_t)(g * 64 + lane) * HH);
#pragma unroll
    for (int i = 0; i < HH / 4; ++i) { wi4[i] = si[i]; wh4[i] = sh[i]; }
  }
  float bi = bih[g * 64 + lane], bh = bhh[g * 64 + lane];

  __shared__ __align__(16) float x_sh[2][HH];   // x ring
  __shared__ __align__(16) float hbr[2][HH];    // h ring
  __shared__ float r_sh[HH], z_sh[HH];
  const float* xbase = hbuf + ((size_t)(b * SS) * NN + n) * HH;
  float hj = 0.f;                      // live on wave 2
  if (g == 0) x_sh[0][lane] = xbase[lane];      // coalesced 256B
  if (g == 2) hbr[0][lane] = 0.f;
  __syncthreads();

#pragma unroll 1
  for (int t = 0; t < SS; ++t) {
    float xnext;
    if (g == 0 && t + 1 < SS)
      xnext = xbase[(size_t)(t + 1) * NN * HH + lane];  // issue early
    const float4* xb = (const float4*)x_sh[t & 1];
    const float4* hb = (const float4*)hbr[t & 1];
    float4 gia = {bi, 0.f, 0.f, 0.f}, gha = {bh, 0.f, 0.f, 0.f};
#pragma unroll
    for (int k = 0; k < HH / 4; ++k) {
      gia += xb[k] * wi4[k];
      gha += hb[k] * wh4[k];
    }
    float gi = sum4(gia), gh = sum4(gha);
    if (g == 0) {
      r_sh[lane] = sigmoidf_(gi + gh);
      if (t + 1 < SS) x_sh[(t + 1) & 1][lane] = xnext;
    } else if (g == 1) {
      z_sh[lane] = sigmoidf_(gi + gh);
    }
    __syncthreads();
    if (g == 2) {
      float rg = r_sh[lane], zg = z_sh[lane];
      float ng = tanhf(gi + rg * gh);
      hj = (1.f - zg) * ng + zg * hj;
      hbr[(t + 1) & 1][lane] = hj;
    }
    __syncthreads();
  }

  // fused heads on wave 0: lanes 0-31 order head, 32-63 demand head
  if (g == 0) {
    const float* hs = hbr[SS & 1];     // h_last (SS even -> slot 0)
    int hf = lane >> 5, jp = lane & 31;
    const float* W1 = hf ? dW1 : oW1;
    const float* b1 = hf ? db1 : ob1;
    const float* W2 = hf ? dW2 : oW2;
    const float* b2 = hf ? db2 : ob2;
    float4 wv[HH / 4];
#pragma unroll
    for (int i = 0; i < HH / 4; ++i) wv[i] = ((const float4*)(W1 + jp * HH))[i];
    float4 a4 = {b1[jp], 0.f, 0.f, 0.f};
#pragma unroll
    for (int k = 0; k < HH / 4; ++k) a4 += ((const float4*)hs)[k] * wv[k];
    float val = fmaxf(sum4(a4), 0.f) * W2[jp];
    val += __shfl_down(val, 16, 32);
    val += __shfl_down(val, 8, 32);
    val += __shfl_down(val, 4, 32);
    val += __shfl_down(val, 2, 32);
    val += __shfl_down(val, 1, 32);
    if (jp == 0) out[hf * (BB * NN) + seq] = val + b2[0];
  }
}

// ---------------- launch -----------------------------------------------------
extern "C" void kernel_launch(void* const* d_in, const int* in_sizes, int n_in,
                              void* d_out, int out_size, void* d_ws, size_t ws_size,
                              hipStream_t stream) {
  const float* x       = (const float*)d_in[0];
  const int*   ei      = (const int*)d_in[1];
  const float* in_W    = (const float*)d_in[2];
  const float* in_b    = (const float*)d_in[3];
  const float* gat_Wl  = (const float*)d_in[4];
  const float* gat_bl  = (const float*)d_in[5];
  const float* gat_Wr  = (const float*)d_in[6];
  const float* gat_br  = (const float*)d_in[7];
  const float* gat_att = (const float*)d_in[8];
  const float* gat_bias= (const float*)d_in[9];
  const float* gru_Wih = (const float*)d_in[10];
  const float* gru_Whh = (const float*)d_in[11];
  const float* gru_bih = (const float*)d_in[12];
  const float* gru_bhh = (const float*)d_in[13];
  const float* oh_W1   = (const float*)d_in[14];
  const float* oh_b1   = (const float*)d_in[15];
  const float* oh_W2   = (const float*)d_in[16];
  const float* oh_b2   = (const float*)d_in[17];
  const float* dh_W1   = (const float*)d_in[18];
  const float* dh_b1   = (const float*)d_in[19];
  const float* dh_W2   = (const float*)d_in[20];
  const float* dh_b2   = (const float*)d_in[21];
  float* out = (float*)d_out;

  char* ws = (char*)d_ws;
  size_t hbytes = (size_t)BB * SS * NN * HH * sizeof(float);   // 33.5 MB
  float* hbuf = (float*)ws;
  int* csr_off = (int*)(ws + hbytes);
  int* csr_src = csr_off + 160;
  int* csr_tgt = csr_src + ET;

  setup_csr_kernel<<<1, 256, 0, stream>>>(ei, csr_off, csr_src, csr_tgt);
  input_proj2_kernel<<<(BB * SS * NN) / 128, 256, 0, stream>>>(x, in_W, in_b, hbuf);
  gat_fused4_kernel<<<BB * SS, 256, 0, stream>>>(
      hbuf, csr_off, csr_src, csr_tgt,
      gat_Wl, gat_bl, gat_Wr, gat_br, gat_att, gat_bias);
  gat_fused4_kernel<<<BB * SS, 256, 0, stream>>>(
      hbuf, csr_off, csr_src, csr_tgt,
      gat_Wl + HH * HH, gat_bl + HH, gat_Wr + HH * HH, gat_br + HH,
      gat_att + HH, gat_bias + HH);
  gru_ws4_kernel<<<BB * NN, 192, 0, stream>>>(
      hbuf, gru_Wih, gru_Whh, gru_bih, gru_bhh,
      oh_W1, oh_b1, oh_W2, oh_b2, dh_W1, dh_b1, dh_W2, dh_b2, out);
}